// Round 1
// baseline (594.610 us; speedup 1.0000x reference)
//
#include <hip/hip_runtime.h>

#define NX 256
#define NU 128
#define NY 128
#define BSZ 128
#define TT 2048
#define LCH 32
#define KCH 64

typedef _Float16 h8 __attribute__((ext_vector_type(8)));
typedef _Float16 h4 __attribute__((ext_vector_type(4)));
typedef float f4 __attribute__((ext_vector_type(4)));

__device__ __forceinline__ f4 mfma16(h8 a, h8 b, f4 c) {
  return __builtin_amdgcn_mfma_f32_16x16x32_f16(a, b, c, 0, 0, 0);
}
// XOR swizzle for 512-byte rows (256 halves) and 256-byte rows (128 halves)
__device__ __forceinline__ int swz512(int row, int bc) { return row * 512 + (bc ^ ((row & 7) << 4)); }
__device__ __forceinline__ int swz256(int row, int bc) { return row * 256 + (bc ^ ((row & 7) << 4)); }

__device__ __forceinline__ h8 cvt8(f4 lo, f4 hi) {
  h8 h;
#pragma unroll
  for (int j = 0; j < 4; ++j) { h[j] = (_Float16)lo[j]; h[j + 4] = (_Float16)hi[j]; }
  return h;
}
__device__ __forceinline__ h8 h8zero() {
  h8 h;
#pragma unroll
  for (int j = 0; j < 8; ++j) h[j] = (_Float16)0.0f;
  return h;
}

// ---------------- setup: E = 0.5*(M1 M1^T + M2 M2^T) + tol I ; F = M2 M1^T ----------------
__global__ __launch_bounds__(256) void k_ef(const float* __restrict__ M,
                                            float* __restrict__ E, float* __restrict__ F) {
  __shared__ float Pt[32][33], Qt[32][33];
  int z = blockIdx.x >> 6;          // 0: E, 1: F
  int tile = blockIdx.x & 63;
  int i0 = (tile >> 3) * 32, j0 = (tile & 7) * 32;
  int tx = threadIdx.x & 15, ty = threadIdx.x >> 4;
  float acc[2][2] = {{0.f, 0.f}, {0.f, 0.f}};
  int np = (z == 0) ? 2 : 1;
  for (int p = 0; p < np; ++p) {
    int po = (z == 0) ? p * 256 : 256;   // P row offset
    int qo = (z == 0) ? p * 256 : 0;     // Q row offset
    for (int kk = 0; kk < 512; kk += 32) {
#pragma unroll
      for (int s = 0; s < 4; ++s) {
        int e = threadIdx.x + s * 256;
        int r = e >> 5, c = e & 31;
        Pt[r][c] = M[(size_t)(i0 + po + r) * 512 + kk + c];
        Qt[r][c] = M[(size_t)(j0 + qo + r) * 512 + kk + c];
      }
      __syncthreads();
#pragma unroll 8
      for (int k = 0; k < 32; ++k) {
#pragma unroll
        for (int ii = 0; ii < 2; ++ii)
#pragma unroll
          for (int jj = 0; jj < 2; ++jj)
            acc[ii][jj] += Pt[ty * 2 + ii][k] * Qt[tx * 2 + jj][k];
      }
      __syncthreads();
    }
  }
#pragma unroll
  for (int ii = 0; ii < 2; ++ii)
#pragma unroll
    for (int jj = 0; jj < 2; ++jj) {
      int i = i0 + ty * 2 + ii, j = j0 + tx * 2 + jj;
      if (z == 0) {
        float v = 0.5f * acc[ii][jj];
        if (i == j) v += 1e-9f;
        E[i * 256 + j] = v;
      } else {
        F[i * 256 + j] = acc[ii][jj];
      }
    }
}

// Gershgorin bound: c = 1 / max_row_abs_sum(E)  (E symmetric -> column sums)
__global__ __launch_bounds__(256) void k_gersh(const float* __restrict__ E, float* __restrict__ cs) {
  __shared__ float red[256];
  int r = threadIdx.x;
  float s = 0.f;
  for (int j = 0; j < 256; ++j) s += fabsf(E[j * 256 + r]);
  red[r] = s;
  __syncthreads();
  for (int o = 128; o > 0; o >>= 1) {
    if (r < o) red[r] = fmaxf(red[r], red[r + o]);
    __syncthreads();
  }
  if (r == 0) cs[0] = 1.0f / red[0];
}

__global__ __launch_bounds__(256) void k_initX(float* __restrict__ X, const float* __restrict__ cs) {
  X[blockIdx.x * 256 + threadIdx.x] = (blockIdx.x == (int)threadIdx.x) ? cs[0] : 0.0f;
}

// generic 256x256x256 fp32 GEMM; mode 0: dst = a*b ; mode 1: dst = 2a - a*b (Newton-Schulz)
__global__ __launch_bounds__(256) void gemm256(float* __restrict__ dst, const float* __restrict__ a,
                                               const float* __restrict__ b, int mode) {
  __shared__ float At[32][33], Bt[32][33];
  int i0 = (blockIdx.x >> 3) * 32, j0 = (blockIdx.x & 7) * 32;
  int tx = threadIdx.x & 15, ty = threadIdx.x >> 4;
  float acc[2][2] = {{0.f, 0.f}, {0.f, 0.f}};
  for (int kk = 0; kk < 256; kk += 32) {
#pragma unroll
    for (int s = 0; s < 4; ++s) {
      int e = threadIdx.x + s * 256;
      int r = e >> 5, c = e & 31;
      At[r][c] = a[(size_t)(i0 + r) * 256 + kk + c];
      Bt[r][c] = b[(size_t)(kk + r) * 256 + j0 + c];
    }
    __syncthreads();
#pragma unroll 8
    for (int k = 0; k < 32; ++k) {
#pragma unroll
      for (int ii = 0; ii < 2; ++ii)
#pragma unroll
        for (int jj = 0; jj < 2; ++jj)
          acc[ii][jj] += At[ty * 2 + ii][k] * Bt[k][tx * 2 + jj];
    }
    __syncthreads();
  }
#pragma unroll
  for (int ii = 0; ii < 2; ++ii)
#pragma unroll
    for (int jj = 0; jj < 2; ++jj) {
      int i = i0 + ty * 2 + ii, j = j0 + tx * 2 + jj;
      float v = acc[ii][jj];
      if (mode == 1) v = 2.0f * a[(size_t)i * 256 + j] - v;
      dst[(size_t)i * 256 + j] = v;
    }
}

// cast fp32 weight matrices to fp16
__global__ __launch_bounds__(256) void k_prep16(const float* __restrict__ A, const float* __restrict__ Ah,
                                                const float* __restrict__ B, const float* __restrict__ C,
                                                const float* __restrict__ D, _Float16* __restrict__ A16,
                                                _Float16* __restrict__ Ah16, _Float16* __restrict__ B16,
                                                _Float16* __restrict__ C16, _Float16* __restrict__ D16) {
  int i = blockIdx.x * 256 + threadIdx.x;
  if (i < 65536) A16[i] = (_Float16)A[i];
  else if (i < 131072) Ah16[i - 65536] = (_Float16)Ah[i - 65536];
  else if (i < 163840) B16[i - 131072] = (_Float16)B[i - 131072];
  else if (i < 196608) C16[i - 163840] = (_Float16)C[i - 163840];
  else D16[i - 196608] = (_Float16)D[i - 196608];
}

// ---------------- phase A: per-chunk zero-state increment w_k ----------------
__global__ __launch_bounds__(512, 2) void k_phaseA(const float* __restrict__ u,
                                                   const _Float16* __restrict__ A16,
                                                   const _Float16* __restrict__ B16,
                                                   float* __restrict__ w) {
  __shared__ __align__(16) char sm[16384];
  char* xb = sm;          // [16][256] halves, swizzled 512B rows
  char* ub = sm + 8192;   // 2 x [16][128] halves, swizzled 256B rows
  int tid = threadIdx.x, lane = tid & 63, wv = tid >> 6;
  int g = lane >> 4, lr = lane & 15;
  int chunk = blockIdx.x >> 3, btile = blockIdx.x & 7;
  int b0 = btile * 16;
  int t0 = chunk * LCH;
  int nt0 = wv * 2;

  h8 Ar[2][8], Bf[2][4];
#pragma unroll
  for (int n2 = 0; n2 < 2; ++n2) {
#pragma unroll
    for (int kf = 0; kf < 8; ++kf)
      Ar[n2][kf] = *(const h8*)(A16 + (size_t)((nt0 + n2) * 16 + lr) * NX + kf * 32 + g * 8);
#pragma unroll
    for (int kf = 0; kf < 4; ++kf)
      Bf[n2][kf] = *(const h8*)(B16 + (size_t)((nt0 + n2) * 16 + lr) * NU + kf * 32 + g * 8);
  }
  int urow = tid >> 5, uuc = tid & 31;
  const float* ubase = u + (size_t)(b0 + urow) * (TT * NU) + uuc * 4;
  {
    f4 raw = *(const f4*)(ubase + (size_t)t0 * NU);
    h4 h;
#pragma unroll
    for (int j = 0; j < 4; ++j) h[j] = (_Float16)raw[j];
    *(h4*)(ub + swz256(urow, uuc * 8)) = h;
  }
  __syncthreads();

  h8 af[8];
#pragma unroll
  for (int kf = 0; kf < 8; ++kf) af[kf] = h8zero();

  f4 z4 = {0.f, 0.f, 0.f, 0.f};
  f4 xacc[2];
  for (int i = 0; i < LCH; ++i) {
    int cur = i & 1;
    int nt = t0 + i + 1;
    if (nt > TT - 1) nt = TT - 1;
    f4 nraw = *(const f4*)(ubase + (size_t)nt * NU);
    xacc[0] = z4; xacc[1] = z4;
#pragma unroll
    for (int kf = 0; kf < 8; ++kf) {
      xacc[0] = mfma16(af[kf], Ar[0][kf], xacc[0]);
      xacc[1] = mfma16(af[kf], Ar[1][kf], xacc[1]);
    }
#pragma unroll
    for (int kf = 0; kf < 4; ++kf) {
      h8 uf = *(const h8*)(ub + cur * 4096 + swz256(lr, kf * 64 + g * 16));
      xacc[0] = mfma16(uf, Bf[0][kf], xacc[0]);
      xacc[1] = mfma16(uf, Bf[1][kf], xacc[1]);
    }
    if (i == LCH - 1) break;
    __syncthreads();
#pragma unroll
    for (int n2 = 0; n2 < 2; ++n2)
#pragma unroll
      for (int r = 0; r < 4; ++r) {
        int row = g * 4 + r;
        *(_Float16*)(xb + swz512(row, ((nt0 + n2) * 16 + lr) * 2)) = (_Float16)xacc[n2][r];
      }
    {
      h4 h;
#pragma unroll
      for (int j = 0; j < 4; ++j) h[j] = (_Float16)nraw[j];
      *(h4*)(ub + (cur ^ 1) * 4096 + swz256(urow, uuc * 8)) = h;
    }
    __syncthreads();
#pragma unroll
    for (int kf = 0; kf < 8; ++kf)
      af[kf] = *(const h8*)(xb + swz512(lr, kf * 64 + g * 16));
  }
#pragma unroll
  for (int n2 = 0; n2 < 2; ++n2)
#pragma unroll
    for (int r = 0; r < 4; ++r)
      w[(size_t)(chunk * BSZ + b0 + g * 4 + r) * NX + (nt0 + n2) * 16 + lr] = xacc[n2][r];
}

// ---------------- phase B: sequential chunk combine ----------------
__global__ __launch_bounds__(512, 2) void k_phaseB(const float* __restrict__ x0,
                                                   const float* __restrict__ w,
                                                   const _Float16* __restrict__ Ah16,
                                                   float* __restrict__ xs) {
  __shared__ __align__(16) char xb[8192];
  int tid = threadIdx.x, lane = tid & 63, wv = tid >> 6;
  int g = lane >> 4, lr = lane & 15;
  int b0 = blockIdx.x * 16;
  int nt0 = wv * 2;
  h8 Ar[2][8];
#pragma unroll
  for (int n2 = 0; n2 < 2; ++n2)
#pragma unroll
    for (int kf = 0; kf < 8; ++kf)
      Ar[n2][kf] = *(const h8*)(Ah16 + (size_t)((nt0 + n2) * 16 + lr) * NX + kf * 32 + g * 8);
  // xs[0] = broadcast x0
  for (int s = 0; s < 8; ++s) {
    int e = tid + s * 512;
    int row = e >> 8, c = e & 255;
    xs[(size_t)(b0 + row) * NX + c] = x0[c];
  }
  h8 af[8];
#pragma unroll
  for (int kf = 0; kf < 8; ++kf) {
    const float* sp = x0 + kf * 32 + g * 8;
    af[kf] = cvt8(*(const f4*)sp, *(const f4*)(sp + 4));
  }
  f4 z4 = {0.f, 0.f, 0.f, 0.f};
  for (int k = 0; k < KCH - 1; ++k) {
    float wl[2][4];
#pragma unroll
    for (int n2 = 0; n2 < 2; ++n2)
#pragma unroll
      for (int r = 0; r < 4; ++r)
        wl[n2][r] = w[(size_t)(k * BSZ + b0 + g * 4 + r) * NX + (nt0 + n2) * 16 + lr];
    f4 acc[2] = {z4, z4};
#pragma unroll
    for (int kf = 0; kf < 8; ++kf) {
      acc[0] = mfma16(af[kf], Ar[0][kf], acc[0]);
      acc[1] = mfma16(af[kf], Ar[1][kf], acc[1]);
    }
#pragma unroll
    for (int n2 = 0; n2 < 2; ++n2)
#pragma unroll
      for (int r = 0; r < 4; ++r) acc[n2][r] += wl[n2][r];
    __syncthreads();
#pragma unroll
    for (int n2 = 0; n2 < 2; ++n2)
#pragma unroll
      for (int r = 0; r < 4; ++r) {
        int row = g * 4 + r;
        *(_Float16*)(xb + swz512(row, ((nt0 + n2) * 16 + lr) * 2)) = (_Float16)acc[n2][r];
        xs[(size_t)((k + 1) * BSZ + b0 + g * 4 + r) * NX + (nt0 + n2) * 16 + lr] = acc[n2][r];
      }
    __syncthreads();
#pragma unroll
    for (int kf = 0; kf < 8; ++kf)
      af[kf] = *(const h8*)(xb + swz512(lr, kf * 64 + g * 16));
  }
}

// ---------------- phase C: per-chunk recurrence + outputs ----------------
__global__ __launch_bounds__(512, 2) void k_phaseC(const float* __restrict__ u,
                                                   const _Float16* __restrict__ A16,
                                                   const _Float16* __restrict__ B16,
                                                   const _Float16* __restrict__ C16,
                                                   const _Float16* __restrict__ D16,
                                                   const float* __restrict__ xs,
                                                   float* __restrict__ out) {
  __shared__ __align__(16) char sm[16384];
  char* xb = sm;
  char* ub = sm + 8192;
  int tid = threadIdx.x, lane = tid & 63, wv = tid >> 6;
  int g = lane >> 4, lr = lane & 15;
  int chunk = blockIdx.x >> 3, btile = blockIdx.x & 7;
  int b0 = btile * 16;
  int t0 = chunk * LCH;
  int nt0 = wv * 2;

  h8 Ar[2][8], Bf[2][4], Cf[8], Df[4];
#pragma unroll
  for (int n2 = 0; n2 < 2; ++n2) {
#pragma unroll
    for (int kf = 0; kf < 8; ++kf)
      Ar[n2][kf] = *(const h8*)(A16 + (size_t)((nt0 + n2) * 16 + lr) * NX + kf * 32 + g * 8);
#pragma unroll
    for (int kf = 0; kf < 4; ++kf)
      Bf[n2][kf] = *(const h8*)(B16 + (size_t)((nt0 + n2) * 16 + lr) * NU + kf * 32 + g * 8);
  }
#pragma unroll
  for (int kf = 0; kf < 8; ++kf)
    Cf[kf] = *(const h8*)(C16 + (size_t)(wv * 16 + lr) * NX + kf * 32 + g * 8);
#pragma unroll
  for (int kf = 0; kf < 4; ++kf)
    Df[kf] = *(const h8*)(D16 + (size_t)(wv * 16 + lr) * NU + kf * 32 + g * 8);

  // af = fragments of chunk's initial state xs[chunk]
  h8 af[8];
#pragma unroll
  for (int kf = 0; kf < 8; ++kf) {
    const float* sp = xs + (size_t)(chunk * BSZ + b0 + lr) * NX + kf * 32 + g * 8;
    af[kf] = cvt8(*(const f4*)sp, *(const f4*)(sp + 4));
  }
  int urow = tid >> 5, uuc = tid & 31;
  const float* ubase = u + (size_t)(b0 + urow) * (TT * NU) + uuc * 4;
  {
    int uidx0 = (chunk == 0) ? 0 : t0 - 1;
    f4 raw = *(const f4*)(ubase + (size_t)uidx0 * NU);
    h4 h;
#pragma unroll
    for (int j = 0; j < 4; ++j) h[j] = (_Float16)raw[j];
    *(h4*)(ub + swz256(urow, uuc * 8)) = h;
  }
  __syncthreads();

  f4 z4 = {0.f, 0.f, 0.f, 0.f};
  for (int i = 0; i < LCH; ++i) {
    int t = t0 + i;
    int cur = i & 1;
    f4 nraw = *(const f4*)(ubase + (size_t)t * NU);  // slice u_t feeds step i+1
    bool upd = (i > 0);
    f4 xacc[2];
    if (upd) {
      xacc[0] = z4; xacc[1] = z4;
#pragma unroll
      for (int kf = 0; kf < 8; ++kf) {
        xacc[0] = mfma16(af[kf], Ar[0][kf], xacc[0]);
        xacc[1] = mfma16(af[kf], Ar[1][kf], xacc[1]);
      }
#pragma unroll
      for (int kf = 0; kf < 4; ++kf) {
        h8 uf = *(const h8*)(ub + cur * 4096 + swz256(lr, kf * 64 + g * 16));
        xacc[0] = mfma16(uf, Bf[0][kf], xacc[0]);
        xacc[1] = mfma16(uf, Bf[1][kf], xacc[1]);
      }
    }
    __syncthreads();
    if (upd) {
#pragma unroll
      for (int n2 = 0; n2 < 2; ++n2)
#pragma unroll
        for (int r = 0; r < 4; ++r) {
          int row = g * 4 + r;
          *(_Float16*)(xb + swz512(row, ((nt0 + n2) * 16 + lr) * 2)) = (_Float16)xacc[n2][r];
        }
    }
    {
      h4 h;
#pragma unroll
      for (int j = 0; j < 4; ++j) h[j] = (_Float16)nraw[j];
      *(h4*)(ub + (cur ^ 1) * 4096 + swz256(urow, uuc * 8)) = h;
    }
    __syncthreads();
    if (upd) {
#pragma unroll
      for (int kf = 0; kf < 8; ++kf)
        af[kf] = *(const h8*)(xb + swz512(lr, kf * 64 + g * 16));
    }
    f4 yacc = z4;
#pragma unroll
    for (int kf = 0; kf < 8; ++kf) yacc = mfma16(af[kf], Cf[kf], yacc);
#pragma unroll
    for (int kf = 0; kf < 4; ++kf) {
      h8 uf = *(const h8*)(ub + cur * 4096 + swz256(lr, kf * 64 + g * 16));
      yacc = mfma16(uf, Df[kf], yacc);
    }
#pragma unroll
    for (int r = 0; r < 4; ++r) {
      int b = b0 + g * 4 + r;
      out[(size_t)b * (TT * NY) + (size_t)t * NY + wv * 16 + lr] = yacc[r];
    }
  }
}

extern "C" void kernel_launch(void* const* d_in, const int* in_sizes, int n_in,
                              void* d_out, int out_size, void* d_ws, size_t ws_size,
                              hipStream_t stream) {
  const float* u  = (const float*)d_in[0];
  const float* M  = (const float*)d_in[1];
  const float* B  = (const float*)d_in[2];
  const float* C  = (const float*)d_in[3];
  const float* D  = (const float*)d_in[4];
  const float* x0 = (const float*)d_in[5];
  float* out = (float*)d_out;
  char* ws = (char*)d_ws;

  float* E    = (float*)(ws + 0L);
  float* F    = (float*)(ws + 256L * 1024);
  float* X    = (float*)(ws + 512L * 1024);
  float* Y    = (float*)(ws + 768L * 1024);
  float* X2   = (float*)(ws + 1024L * 1024);
  float* Amat = (float*)(ws + 1280L * 1024);
  float* P1   = (float*)(ws + 1536L * 1024);
  float* P2   = (float*)(ws + 1792L * 1024);
  float* cs   = (float*)(ws + 2048L * 1024);
  _Float16* A16  = (_Float16*)(ws + 2304L * 1024);
  _Float16* Ah16 = (_Float16*)(ws + 2432L * 1024);
  _Float16* B16  = (_Float16*)(ws + 2560L * 1024);
  _Float16* C16  = (_Float16*)(ws + 2624L * 1024);
  _Float16* D16  = (_Float16*)(ws + 2688L * 1024);
  float* wbuf = (float*)(ws + 2816L * 1024);              // 8 MB
  float* xs   = (float*)(ws + (2816L + 8192L) * 1024);    // 8 MB

  k_ef<<<128, 256, 0, stream>>>(M, E, F);
  k_gersh<<<1, 256, 0, stream>>>(E, cs);
  k_initX<<<256, 256, 0, stream>>>(X, cs);
  // Newton-Schulz: X <- X(2I - E X), 11 iterations
  float *xc = X, *xn = X2;
  for (int it = 0; it < 11; ++it) {
    gemm256<<<64, 256, 0, stream>>>(Y, E, xc, 0);
    gemm256<<<64, 256, 0, stream>>>(xn, xc, Y, 1);
    float* tmp = xc; xc = xn; xn = tmp;
  }
  gemm256<<<64, 256, 0, stream>>>(Amat, xc, F, 0);   // A = E^-1 F
  // A^32 by repeated squaring
  gemm256<<<64, 256, 0, stream>>>(P1, Amat, Amat, 0); // A^2
  gemm256<<<64, 256, 0, stream>>>(P2, P1, P1, 0);     // A^4
  gemm256<<<64, 256, 0, stream>>>(P1, P2, P2, 0);     // A^8
  gemm256<<<64, 256, 0, stream>>>(P2, P1, P1, 0);     // A^16
  gemm256<<<64, 256, 0, stream>>>(P1, P2, P2, 0);     // A^32
  k_prep16<<<832, 256, 0, stream>>>(Amat, P1, B, C, D, A16, Ah16, B16, C16, D16);

  k_phaseA<<<512, 512, 0, stream>>>(u, A16, B16, wbuf);
  k_phaseB<<<8, 512, 0, stream>>>(x0, wbuf, Ah16, xs);
  k_phaseC<<<512, 512, 0, stream>>>(u, A16, B16, C16, D16, xs, out);
}

// Round 2
// 502.515 us; speedup vs baseline: 1.1833x; 1.1833x over previous
//
#include <hip/hip_runtime.h>

#define NX 256
#define NU 128
#define NY 128
#define BSZ 128
#define TT 2048
#define LCH 32
#define KCH 64

typedef _Float16 h8 __attribute__((ext_vector_type(8)));
typedef _Float16 h4 __attribute__((ext_vector_type(4)));
typedef float f4 __attribute__((ext_vector_type(4)));

__device__ __forceinline__ f4 mfma16(h8 a, h8 b, f4 c) {
  return __builtin_amdgcn_mfma_f32_16x16x32_f16(a, b, c, 0, 0, 0);
}
// u LDS: [16][128] h16, 256B rows
__device__ __forceinline__ int swz256(int row, int bc) { return row * 256 + (bc ^ ((row & 7) << 4)); }
// x LDS: [16][256] h16, 512B rows. byte(br,sc) = br*512 + ((sc*2) ^ ((br>>2)<<5))
__device__ __forceinline__ int xwr(int br, int sc) { return br * 512 + ((sc * 2) ^ ((br >> 2) << 5)); }
__device__ __forceinline__ int xrd(int lr, int bytec) { return lr * 512 + (bytec ^ ((lr >> 2) << 5)); }

__device__ __forceinline__ h8 cvt8(f4 lo, f4 hi) {
  h8 h;
#pragma unroll
  for (int j = 0; j < 4; ++j) { h[j] = (_Float16)lo[j]; h[j + 4] = (_Float16)hi[j]; }
  return h;
}
__device__ __forceinline__ h8 h8zero() {
  h8 h;
#pragma unroll
  for (int j = 0; j < 8; ++j) h[j] = (_Float16)0.0f;
  return h;
}

// ---------------- E = 0.5*(M1 M1^T + M2 M2^T) + tol I ; F = M2 M1^T ; B16 cast ----------------
__global__ __launch_bounds__(256) void k_ef(const float* __restrict__ M, const float* __restrict__ B,
                                            float* __restrict__ E, float* __restrict__ F,
                                            _Float16* __restrict__ B16) {
  __shared__ float Pt[32][33], Qt[32][33];
  int z = blockIdx.x >> 6;
  int tile = blockIdx.x & 63;
  int i0 = (tile >> 3) * 32, j0 = (tile & 7) * 32;
  int tx = threadIdx.x & 15, ty = threadIdx.x >> 4;
  float acc[2][2] = {{0.f, 0.f}, {0.f, 0.f}};
  int np = (z == 0) ? 2 : 1;
  for (int p = 0; p < np; ++p) {
    int po = (z == 0) ? p * 256 : 256;
    int qo = (z == 0) ? p * 256 : 0;
    for (int kk = 0; kk < 512; kk += 32) {
#pragma unroll
      for (int s = 0; s < 4; ++s) {
        int e = threadIdx.x + s * 256;
        int r = e >> 5, c = e & 31;
        Pt[r][c] = M[(size_t)(i0 + po + r) * 512 + kk + c];
        Qt[r][c] = M[(size_t)(j0 + qo + r) * 512 + kk + c];
      }
      __syncthreads();
#pragma unroll 8
      for (int k = 0; k < 32; ++k) {
#pragma unroll
        for (int ii = 0; ii < 2; ++ii)
#pragma unroll
          for (int jj = 0; jj < 2; ++jj)
            acc[ii][jj] += Pt[ty * 2 + ii][k] * Qt[tx * 2 + jj][k];
      }
      __syncthreads();
    }
  }
#pragma unroll
  for (int ii = 0; ii < 2; ++ii)
#pragma unroll
    for (int jj = 0; jj < 2; ++jj) {
      int i = i0 + ty * 2 + ii, j = j0 + tx * 2 + jj;
      if (z == 0) {
        float v = 0.5f * acc[ii][jj];
        if (i == j) v += 1e-9f;
        E[i * 256 + j] = v;
      } else {
        F[i * 256 + j] = acc[ii][jj];
      }
    }
  int idx = blockIdx.x * 256 + threadIdx.x;
  if (idx < NX * NU) B16[idx] = (_Float16)B[idx];
}

// ---------------- lambda_max estimate: c = ||E v|| / ||E^2 v||, v = ones ----------------
__global__ __launch_bounds__(256) void k_pow(const float* __restrict__ E, float* __restrict__ cs) {
  __shared__ __align__(16) float v[256];
  __shared__ float red[256];
  int i = threadIdx.x;
  v[i] = 1.0f;
  __syncthreads();
  float n1 = 0.f, n2 = 0.f;
  for (int it = 0; it < 2; ++it) {
    float s = 0.f;
    const float* row = E + (size_t)i * 256;
#pragma unroll 8
    for (int j = 0; j < 256; j += 4) {
      f4 e = *(const f4*)(row + j);
      f4 vv = *(const f4*)(&v[j]);
      s += e[0] * vv[0] + e[1] * vv[1] + e[2] * vv[2] + e[3] * vv[3];
    }
    red[i] = s * s;
    __syncthreads();
    for (int o = 128; o > 0; o >>= 1) {
      if (i < o) red[i] += red[i + o];
      __syncthreads();
    }
    if (it == 0) n1 = red[0]; else n2 = red[0];
    __syncthreads();
    v[i] = s;
    __syncthreads();
  }
  if (i == 0) cs[0] = sqrtf(n1 / n2);  // 1 / lambda_est, lambda_est <= lambda_max
}

// ---------------- NS init: T = E*E ; Y1 = 2cE - c^2 T ; X1 = 2cI - c^2 E ----------------
__global__ __launch_bounds__(256) void k_ns1(const float* __restrict__ E, const float* __restrict__ cs,
                                             float* __restrict__ X, float* __restrict__ Y) {
  __shared__ float At[32][33], Bt[32][33];
  int i0 = (blockIdx.x >> 3) * 32, j0 = (blockIdx.x & 7) * 32;
  int tx = threadIdx.x & 15, ty = threadIdx.x >> 4;
  float acc[2][2] = {{0.f, 0.f}, {0.f, 0.f}};
  for (int kk = 0; kk < 256; kk += 32) {
#pragma unroll
    for (int s = 0; s < 4; ++s) {
      int e = threadIdx.x + s * 256;
      int r = e >> 5, c = e & 31;
      At[r][c] = E[(size_t)(i0 + r) * 256 + kk + c];
      Bt[r][c] = E[(size_t)(kk + r) * 256 + j0 + c];
    }
    __syncthreads();
#pragma unroll 8
    for (int k = 0; k < 32; ++k) {
#pragma unroll
      for (int ii = 0; ii < 2; ++ii)
#pragma unroll
        for (int jj = 0; jj < 2; ++jj)
          acc[ii][jj] += At[ty * 2 + ii][k] * Bt[k][tx * 2 + jj];
    }
    __syncthreads();
  }
  float c = cs[0];
#pragma unroll
  for (int ii = 0; ii < 2; ++ii)
#pragma unroll
    for (int jj = 0; jj < 2; ++jj) {
      int i = i0 + ty * 2 + ii, j = j0 + tx * 2 + jj;
      float e = E[(size_t)i * 256 + j];
      Y[(size_t)i * 256 + j] = 2.f * c * e - c * c * acc[ii][jj];
      X[(size_t)i * 256 + j] = (i == j ? 2.f * c : 0.f) - c * c * e;
    }
}

// ---------------- fused NS pair: Xn = 2X - X*Y ; Yn = 2Y - Y*Y ----------------
__global__ __launch_bounds__(256) void k_nspair(const float* __restrict__ Xc, const float* __restrict__ Yc,
                                                float* __restrict__ Xn, float* __restrict__ Yn) {
  __shared__ float At[32][33], Bt[32][33];
  int z = blockIdx.x >> 6;
  int tile = blockIdx.x & 63;
  const float* a = z ? Yc : Xc;
  float* d = z ? Yn : Xn;
  int i0 = (tile >> 3) * 32, j0 = (tile & 7) * 32;
  int tx = threadIdx.x & 15, ty = threadIdx.x >> 4;
  float acc[2][2] = {{0.f, 0.f}, {0.f, 0.f}};
  for (int kk = 0; kk < 256; kk += 32) {
#pragma unroll
    for (int s = 0; s < 4; ++s) {
      int e = threadIdx.x + s * 256;
      int r = e >> 5, c = e & 31;
      At[r][c] = a[(size_t)(i0 + r) * 256 + kk + c];
      Bt[r][c] = Yc[(size_t)(kk + r) * 256 + j0 + c];
    }
    __syncthreads();
#pragma unroll 8
    for (int k = 0; k < 32; ++k) {
#pragma unroll
      for (int ii = 0; ii < 2; ++ii)
#pragma unroll
        for (int jj = 0; jj < 2; ++jj)
          acc[ii][jj] += At[ty * 2 + ii][k] * Bt[k][tx * 2 + jj];
    }
    __syncthreads();
  }
#pragma unroll
  for (int ii = 0; ii < 2; ++ii)
#pragma unroll
    for (int jj = 0; jj < 2; ++jj) {
      int i = i0 + ty * 2 + ii, j = j0 + tx * 2 + jj;
      d[(size_t)i * 256 + j] = 2.f * a[(size_t)i * 256 + j] - acc[ii][jj];
    }
}

// ---------------- generic fp32 GEMM: d = a*b (+adds), optional f32/h16 outputs ----------------
__global__ __launch_bounds__(256) void k_gemm(const float* __restrict__ a, const float* __restrict__ b,
                                              const float* __restrict__ adds, float* __restrict__ d32,
                                              _Float16* __restrict__ d16, int Nd, int Kd) {
  __shared__ float At[32][33], Bt[32][33];
  int ntile = Nd >> 5;
  int i0 = (blockIdx.x / ntile) * 32, j0 = (blockIdx.x % ntile) * 32;
  int tx = threadIdx.x & 15, ty = threadIdx.x >> 4;
  float acc[2][2] = {{0.f, 0.f}, {0.f, 0.f}};
  for (int kk = 0; kk < Kd; kk += 32) {
#pragma unroll
    for (int s = 0; s < 4; ++s) {
      int e = threadIdx.x + s * 256;
      int r = e >> 5, c = e & 31;
      At[r][c] = a[(size_t)(i0 + r) * Kd + kk + c];
      Bt[r][c] = b[(size_t)(kk + r) * Nd + j0 + c];
    }
    __syncthreads();
#pragma unroll 8
    for (int k = 0; k < 32; ++k) {
#pragma unroll
      for (int ii = 0; ii < 2; ++ii)
#pragma unroll
        for (int jj = 0; jj < 2; ++jj)
          acc[ii][jj] += At[ty * 2 + ii][k] * Bt[k][tx * 2 + jj];
    }
    __syncthreads();
  }
#pragma unroll
  for (int ii = 0; ii < 2; ++ii)
#pragma unroll
    for (int jj = 0; jj < 2; ++jj) {
      int i = i0 + ty * 2 + ii, j = j0 + tx * 2 + jj;
      float v = acc[ii][jj];
      if (adds) v += adds[(size_t)i * Nd + j];
      if (d32) d32[(size_t)i * Nd + j] = v;
      if (d16) d16[(size_t)i * Nd + j] = (_Float16)v;
    }
}

// ---------------- y(0) = C x0 + D u[:,0], exact fp32 ----------------
__global__ __launch_bounds__(512) void k_y0(const float* __restrict__ C, const float* __restrict__ D,
                                            const float* __restrict__ x0, const float* __restrict__ u,
                                            float* __restrict__ out) {
  int idx = blockIdx.x * 512 + threadIdx.x;  // 0..16383
  int b = idx >> 7, col = idx & 127;
  const float* crow = C + (size_t)col * 256;
  const float* drow = D + (size_t)col * 128;
  const float* ur = u + (size_t)b * (TT * NU);
  float s = 0.f;
#pragma unroll 8
  for (int j = 0; j < 256; j += 4) {
    f4 cv = *(const f4*)(crow + j);
    f4 xv = *(const f4*)(x0 + j);
    s += cv[0] * xv[0] + cv[1] * xv[1] + cv[2] * xv[2] + cv[3] * xv[3];
  }
#pragma unroll 8
  for (int j = 0; j < 128; j += 4) {
    f4 dv = *(const f4*)(drow + j);
    f4 uv = *(const f4*)(ur + j);
    s += dv[0] * uv[0] + dv[1] * uv[1] + dv[2] * uv[2] + dv[3] * uv[3];
  }
  out[(size_t)b * (TT * NY) + col] = s;
}

// ---------------- phase A: per-chunk zero-state increment w_k ----------------
__global__ __launch_bounds__(512, 2) void k_phaseA(const float* __restrict__ u,
                                                   const _Float16* __restrict__ A16,
                                                   const _Float16* __restrict__ B16,
                                                   float* __restrict__ w) {
  __shared__ __align__(16) char sm[24576];
  char* xb = sm;            // 2 x [16][256] h16
  char* ub = sm + 16384;    // 2 x [16][128] h16
  int tid = threadIdx.x, lane = tid & 63, wv = tid >> 6;
  int g = lane >> 4, lr = lane & 15;
  int chunk = blockIdx.x >> 3, btile = blockIdx.x & 7;
  int b0 = btile * 16, t0 = chunk * LCH, nt0 = wv * 2;

  h8 Ar[2][8], Bf[2][4];
#pragma unroll
  for (int n2 = 0; n2 < 2; ++n2) {
#pragma unroll
    for (int kf = 0; kf < 8; ++kf)
      Ar[n2][kf] = *(const h8*)(A16 + (size_t)((nt0 + n2) * 16 + lr) * NX + kf * 32 + g * 8);
#pragma unroll
    for (int kf = 0; kf < 4; ++kf)
      Bf[n2][kf] = *(const h8*)(B16 + (size_t)((nt0 + n2) * 16 + lr) * NU + kf * 32 + g * 8);
  }
  int urow = tid >> 5, uuc = tid & 31;
  const float* ubase = u + (size_t)(b0 + urow) * (TT * NU) + uuc * 4;
  int uoff = swz256(urow, uuc * 8);
  {
    f4 r0 = *(const f4*)(ubase + (size_t)t0 * NU);
    h4 h;
#pragma unroll
    for (int j = 0; j < 4; ++j) h[j] = (_Float16)r0[j];
    *(h4*)(ub + uoff) = h;
  }
  f4 ureg = *(const f4*)(ubase + (size_t)(t0 + 1) * NU);
  h8 af[8];
#pragma unroll
  for (int kf = 0; kf < 8; ++kf) af[kf] = h8zero();
  __syncthreads();

  f4 z4 = {0.f, 0.f, 0.f, 0.f};
  f4 xacc[2];
#pragma unroll 2
  for (int i = 0; i < LCH; ++i) {
    const int p = i & 1;
    if (i < LCH - 1) {
      h4 h;
#pragma unroll
      for (int j = 0; j < 4; ++j) h[j] = (_Float16)ureg[j];
      *(h4*)(ub + (p ^ 1) * 4096 + uoff) = h;
      int nt = t0 + i + 2;
      if (nt > TT - 1) nt = TT - 1;
      ureg = *(const f4*)(ubase + (size_t)nt * NU);
    }
    h8 uf[4];
#pragma unroll
    for (int kf = 0; kf < 4; ++kf)
      uf[kf] = *(const h8*)(ub + p * 4096 + swz256(lr, kf * 64 + g * 16));
    xacc[0] = z4; xacc[1] = z4;
#pragma unroll
    for (int kf = 0; kf < 8; ++kf) {
      xacc[0] = mfma16(af[kf], Ar[0][kf], xacc[0]);
      xacc[1] = mfma16(af[kf], Ar[1][kf], xacc[1]);
    }
#pragma unroll
    for (int kf = 0; kf < 4; ++kf) {
      xacc[0] = mfma16(uf[kf], Bf[0][kf], xacc[0]);
      xacc[1] = mfma16(uf[kf], Bf[1][kf], xacc[1]);
    }
    if (i < LCH - 1) {
#pragma unroll
      for (int n2 = 0; n2 < 2; ++n2)
#pragma unroll
        for (int r = 0; r < 4; ++r)
          *(_Float16*)(xb + (p ^ 1) * 8192 + xwr(g * 4 + r, (nt0 + n2) * 16 + lr)) = (_Float16)xacc[n2][r];
      __syncthreads();
#pragma unroll
      for (int kf = 0; kf < 8; ++kf)
        af[kf] = *(const h8*)(xb + (p ^ 1) * 8192 + xrd(lr, kf * 64 + g * 16));
    }
  }
#pragma unroll
  for (int n2 = 0; n2 < 2; ++n2)
#pragma unroll
    for (int r = 0; r < 4; ++r)
      w[(size_t)(chunk * BSZ + b0 + g * 4 + r) * NX + (nt0 + n2) * 16 + lr] = xacc[n2][r];
}

// ---------------- phase B: sequential chunk combine (x_{k+1} = A^32 x_k + w_k) ----------------
__global__ __launch_bounds__(512, 2) void k_phaseB(const float* __restrict__ x0,
                                                   const float* __restrict__ w,
                                                   const _Float16* __restrict__ Ah16,
                                                   float* __restrict__ xs) {
  __shared__ __align__(16) char xb[16384];  // 2 x [16][256] h16
  int tid = threadIdx.x, lane = tid & 63, wv = tid >> 6;
  int g = lane >> 4, lr = lane & 15;
  int b0 = blockIdx.x * 16, nt0 = wv * 2;
  h8 Ar[2][8];
#pragma unroll
  for (int n2 = 0; n2 < 2; ++n2)
#pragma unroll
    for (int kf = 0; kf < 8; ++kf)
      Ar[n2][kf] = *(const h8*)(Ah16 + (size_t)((nt0 + n2) * 16 + lr) * NX + kf * 32 + g * 8);
  for (int s = 0; s < 8; ++s) {
    int e = tid + s * 512;
    int row = e >> 8, c = e & 255;
    xs[(size_t)(b0 + row) * NX + c] = x0[c];
  }
  h8 af[8];
#pragma unroll
  for (int kf = 0; kf < 8; ++kf) {
    const float* sp = x0 + kf * 32 + g * 8;
    af[kf] = cvt8(*(const f4*)sp, *(const f4*)(sp + 4));
  }
  float wl[2][4];
#pragma unroll
  for (int n2 = 0; n2 < 2; ++n2)
#pragma unroll
    for (int r = 0; r < 4; ++r)
      wl[n2][r] = w[(size_t)(b0 + g * 4 + r) * NX + (nt0 + n2) * 16 + lr];
  f4 z4 = {0.f, 0.f, 0.f, 0.f};
  for (int k = 0; k < KCH - 1; ++k) {
    const int p = k & 1;
    float wn[2][4] = {{0.f, 0.f, 0.f, 0.f}, {0.f, 0.f, 0.f, 0.f}};
    if (k < KCH - 2) {
#pragma unroll
      for (int n2 = 0; n2 < 2; ++n2)
#pragma unroll
        for (int r = 0; r < 4; ++r)
          wn[n2][r] = w[(size_t)((k + 1) * BSZ + b0 + g * 4 + r) * NX + (nt0 + n2) * 16 + lr];
    }
    f4 acc[2] = {z4, z4};
#pragma unroll
    for (int kf = 0; kf < 8; ++kf) {
      acc[0] = mfma16(af[kf], Ar[0][kf], acc[0]);
      acc[1] = mfma16(af[kf], Ar[1][kf], acc[1]);
    }
#pragma unroll
    for (int n2 = 0; n2 < 2; ++n2)
#pragma unroll
      for (int r = 0; r < 4; ++r) {
        acc[n2][r] += wl[n2][r];
        xs[(size_t)((k + 1) * BSZ + b0 + g * 4 + r) * NX + (nt0 + n2) * 16 + lr] = acc[n2][r];
      }
    if (k < KCH - 2) {
#pragma unroll
      for (int n2 = 0; n2 < 2; ++n2)
#pragma unroll
        for (int r = 0; r < 4; ++r)
          *(_Float16*)(xb + (p ^ 1) * 8192 + xwr(g * 4 + r, (nt0 + n2) * 16 + lr)) = (_Float16)acc[n2][r];
      __syncthreads();
#pragma unroll
      for (int kf = 0; kf < 8; ++kf)
        af[kf] = *(const h8*)(xb + (p ^ 1) * 8192 + xrd(lr, kf * 64 + g * 16));
    }
#pragma unroll
    for (int n2 = 0; n2 < 2; ++n2)
#pragma unroll
      for (int r = 0; r < 4; ++r) wl[n2][r] = wn[n2][r];
  }
}

// ---------------- phase C: y(t) = CA x(t-1) + CBD u(t-1), x(t) = A x(t-1) + B u(t-1) ----------------
__global__ __launch_bounds__(512, 2) void k_phaseC(const float* __restrict__ u,
                                                   const _Float16* __restrict__ A16,
                                                   const _Float16* __restrict__ B16,
                                                   const _Float16* __restrict__ CA16,
                                                   const _Float16* __restrict__ CBD16,
                                                   const float* __restrict__ xs,
                                                   float* __restrict__ out) {
  __shared__ __align__(16) char sm[24576];
  char* xb = sm;
  char* ub = sm + 16384;
  int tid = threadIdx.x, lane = tid & 63, wv = tid >> 6;
  int g = lane >> 4, lr = lane & 15;
  int chunk = blockIdx.x >> 3, btile = blockIdx.x & 7;
  int b0 = btile * 16, t0 = chunk * LCH, nt0 = wv * 2;

  h8 Ar[2][8], Bf[2][4], Cf[8], Df[4];
#pragma unroll
  for (int n2 = 0; n2 < 2; ++n2) {
#pragma unroll
    for (int kf = 0; kf < 8; ++kf)
      Ar[n2][kf] = *(const h8*)(A16 + (size_t)((nt0 + n2) * 16 + lr) * NX + kf * 32 + g * 8);
#pragma unroll
    for (int kf = 0; kf < 4; ++kf)
      Bf[n2][kf] = *(const h8*)(B16 + (size_t)((nt0 + n2) * 16 + lr) * NU + kf * 32 + g * 8);
  }
#pragma unroll
  for (int kf = 0; kf < 8; ++kf)
    Cf[kf] = *(const h8*)(CA16 + (size_t)(wv * 16 + lr) * NX + kf * 32 + g * 8);
#pragma unroll
  for (int kf = 0; kf < 4; ++kf)
    Df[kf] = *(const h8*)(CBD16 + (size_t)(wv * 16 + lr) * NU + kf * 32 + g * 8);

  h8 af[8];
#pragma unroll
  for (int kf = 0; kf < 8; ++kf) {
    const float* sp = xs + (size_t)(chunk * BSZ + b0 + lr) * NX + kf * 32 + g * 8;
    af[kf] = cvt8(*(const f4*)sp, *(const f4*)(sp + 4));
  }
  int urow = tid >> 5, uuc = tid & 31;
  const float* ubase = u + (size_t)(b0 + urow) * (TT * NU) + uuc * 4;
  int uoff = swz256(urow, uuc * 8);
  {
    f4 r0 = *(const f4*)(ubase + (size_t)t0 * NU);
    h4 h;
#pragma unroll
    for (int j = 0; j < 4; ++j) h[j] = (_Float16)r0[j];
    *(h4*)(ub + uoff) = h;
  }
  f4 ureg = *(const f4*)(ubase + (size_t)(t0 + 1) * NU);
  __syncthreads();

  f4 z4 = {0.f, 0.f, 0.f, 0.f};
#pragma unroll 2
  for (int i = 0; i < LCH; ++i) {
    const int p = i & 1;
    if (i < LCH - 1) {
      h4 h;
#pragma unroll
      for (int j = 0; j < 4; ++j) h[j] = (_Float16)ureg[j];
      *(h4*)(ub + (p ^ 1) * 4096 + uoff) = h;
      int nt = t0 + i + 2;
      if (nt > TT - 1) nt = TT - 1;
      ureg = *(const f4*)(ubase + (size_t)nt * NU);
    }
    h8 uf[4];
#pragma unroll
    for (int kf = 0; kf < 4; ++kf)
      uf[kf] = *(const h8*)(ub + p * 4096 + swz256(lr, kf * 64 + g * 16));
    // y(t) = CA x(t-1) + CBD u(t-1)
    f4 yacc = z4;
#pragma unroll
    for (int kf = 0; kf < 8; ++kf) yacc = mfma16(af[kf], Cf[kf], yacc);
#pragma unroll
    for (int kf = 0; kf < 4; ++kf) yacc = mfma16(uf[kf], Df[kf], yacc);
    int t = t0 + i + 1;
    if (t < TT) {
#pragma unroll
      for (int r = 0; r < 4; ++r)
        out[(size_t)(b0 + g * 4 + r) * (TT * NY) + (size_t)t * NY + wv * 16 + lr] = yacc[r];
    }
    if (i < LCH - 1) {
      f4 xacc[2] = {z4, z4};
#pragma unroll
      for (int kf = 0; kf < 8; ++kf) {
        xacc[0] = mfma16(af[kf], Ar[0][kf], xacc[0]);
        xacc[1] = mfma16(af[kf], Ar[1][kf], xacc[1]);
      }
#pragma unroll
      for (int kf = 0; kf < 4; ++kf) {
        xacc[0] = mfma16(uf[kf], Bf[0][kf], xacc[0]);
        xacc[1] = mfma16(uf[kf], Bf[1][kf], xacc[1]);
      }
#pragma unroll
      for (int n2 = 0; n2 < 2; ++n2)
#pragma unroll
        for (int r = 0; r < 4; ++r)
          *(_Float16*)(xb + (p ^ 1) * 8192 + xwr(g * 4 + r, (nt0 + n2) * 16 + lr)) = (_Float16)xacc[n2][r];
      __syncthreads();
#pragma unroll
      for (int kf = 0; kf < 8; ++kf)
        af[kf] = *(const h8*)(xb + (p ^ 1) * 8192 + xrd(lr, kf * 64 + g * 16));
    }
  }
}

extern "C" void kernel_launch(void* const* d_in, const int* in_sizes, int n_in,
                              void* d_out, int out_size, void* d_ws, size_t ws_size,
                              hipStream_t stream) {
  const float* u  = (const float*)d_in[0];
  const float* M  = (const float*)d_in[1];
  const float* B  = (const float*)d_in[2];
  const float* C  = (const float*)d_in[3];
  const float* D  = (const float*)d_in[4];
  const float* x0 = (const float*)d_in[5];
  float* out = (float*)d_out;
  char* ws = (char*)d_ws;

  float* E    = (float*)(ws + 0L);
  float* F    = (float*)(ws + 256L * 1024);
  float* X1   = (float*)(ws + 512L * 1024);
  float* Y1   = (float*)(ws + 768L * 1024);
  float* X2   = (float*)(ws + 1024L * 1024);
  float* Y2   = (float*)(ws + 1280L * 1024);
  float* Amat = (float*)(ws + 1536L * 1024);
  float* P1   = (float*)(ws + 1792L * 1024);
  float* P2   = (float*)(ws + 2048L * 1024);
  float* cs   = (float*)(ws + 2304L * 1024);
  _Float16* A16   = (_Float16*)(ws + 2368L * 1024);
  _Float16* Ah16  = (_Float16*)(ws + 2496L * 1024);
  _Float16* B16   = (_Float16*)(ws + 2624L * 1024);
  _Float16* CA16  = (_Float16*)(ws + 2688L * 1024);
  _Float16* CBD16 = (_Float16*)(ws + 2752L * 1024);
  float* wbuf = (float*)(ws + 2816L * 1024);             // 8 MB
  float* xs   = (float*)(ws + (2816L + 8192L) * 1024);   // 8 MB

  k_y0<<<32, 512, 0, stream>>>(C, D, x0, u, out);
  k_ef<<<128, 256, 0, stream>>>(M, B, E, F, B16);
  k_pow<<<1, 256, 0, stream>>>(E, cs);
  k_ns1<<<64, 256, 0, stream>>>(E, cs, X1, Y1);
  float *Xc = X1, *Yc = Y1, *Xn = X2, *Yn = Y2;
  for (int it = 0; it < 6; ++it) {
    k_nspair<<<128, 256, 0, stream>>>(Xc, Yc, Xn, Yn);
    float* t1 = Xc; Xc = Xn; Xn = t1;
    float* t2 = Yc; Yc = Yn; Yn = t2;
  }
  k_gemm<<<64, 256, 0, stream>>>(Xc, F, nullptr, Amat, A16, 256, 256);      // A = E^-1 F
  k_gemm<<<64, 256, 0, stream>>>(Amat, Amat, nullptr, P1, nullptr, 256, 256); // A^2
  k_gemm<<<64, 256, 0, stream>>>(P1, P1, nullptr, P2, nullptr, 256, 256);     // A^4
  k_gemm<<<64, 256, 0, stream>>>(P2, P2, nullptr, P1, nullptr, 256, 256);     // A^8
  k_gemm<<<64, 256, 0, stream>>>(P1, P1, nullptr, P2, nullptr, 256, 256);     // A^16
  k_gemm<<<64, 256, 0, stream>>>(P2, P2, nullptr, P1, Ah16, 256, 256);        // A^32
  k_gemm<<<32, 256, 0, stream>>>(C, Amat, nullptr, nullptr, CA16, 256, 256);  // CA
  k_gemm<<<16, 256, 0, stream>>>(C, B, D, nullptr, CBD16, 128, 256);          // CB + D

  k_phaseA<<<512, 512, 0, stream>>>(u, A16, B16, wbuf);
  k_phaseB<<<8, 512, 0, stream>>>(x0, wbuf, Ah16, xs);
  k_phaseC<<<512, 512, 0, stream>>>(u, A16, B16, CA16, CBD16, xs, out);
}